// Round 2
// baseline (819.584 us; speedup 1.0000x reference)
//
#include <hip/hip_runtime.h>
#include <hip/hip_bf16.h>

// DiagonalWindowAttention fused kernel (fp32 baseline).
// One block per window (nw=2048), 256 threads.
//   phase 0 : LayerNorm stats per patch + stage proj_w^T, gamma/beta, proj_b
//   per head: stage qn/k/v 64x64 tiles in LDS -> QK^T (4x4 reg tile) ->
//             +bias+mask -> softmax (shfl over 16 lanes) -> PV -> bf16 out_pre
//   epilogue: fused 256x96 @ 96x96 projection, inverse group permutation store
//
// token grouping: p = wh*8+ww, s = sh*2+sw, sequence idx g = wh*32+sh*16+ww*2+sw

#define TPB 256

__device__ __forceinline__ int seq_of(int p, int s) {
    return ((p >> 3) << 5) | ((s >> 1) << 4) | ((p & 7) << 1) | (s & 1);
}

__global__ __launch_bounds__(TPB)
void dwa_fused(const float* __restrict__ gq,
               const float* __restrict__ gk,
               const float* __restrict__ gv,
               const float* __restrict__ gmask,
               const float* __restrict__ gbt,
               const float* __restrict__ ggamma,
               const float* __restrict__ gbeta,
               const float* __restrict__ gpw,
               const float* __restrict__ gpb,
               float* __restrict__ gout,
               int nwm)
{
    const int w = blockIdx.x;
    const int t = threadIdx.x;

    __shared__ float s_mu[64];
    __shared__ float s_rs[64];
    __shared__ float s_qh[64 * 66];      // q-head tile; reused for attn probs
    __shared__ float s_kh[64 * 66];
    __shared__ float s_vh[64 * 66];
    __shared__ float s_wt[96 * 96];      // proj_w transposed: s_wt[e*96+o] = W[o][e]
    __shared__ float s_gamma[4 * 97];
    __shared__ float s_beta[4 * 97];
    __shared__ float s_pb[96];
    __shared__ __hip_bfloat16 s_pre[256 * 98]; // out_pre[token'][e], token' = p*4+s

    // ---------------- phase 0: LN stats + stage small tensors ----------------
    {
        const int p = t >> 2, s = t & 3;
        const int g = seq_of(p, s);
        const float4* qr = (const float4*)(gq + ((size_t)w * 256 + g) * 96);
        float sum = 0.f, ssq = 0.f;
#pragma unroll
        for (int i = 0; i < 24; ++i) {
            float4 x = qr[i];
            sum += (x.x + x.y) + (x.z + x.w);
            ssq += (x.x * x.x + x.y * x.y) + (x.z * x.z + x.w * x.w);
        }
        sum += __shfl_xor(sum, 1); ssq += __shfl_xor(ssq, 1);
        sum += __shfl_xor(sum, 2); ssq += __shfl_xor(ssq, 2);
        if (s == 0) {
            float mu = sum * (1.f / 384.f);
            float var = ssq * (1.f / 384.f) - mu * mu;
            s_mu[p] = mu;
            s_rs[p] = rsqrtf(var + 1e-5f);
        }
    }
    for (int i = t; i < 96 * 96; i += TPB) {
        // s_wt[i] with i = e*96+o  <=  gpw[o*96+e]  (strided global read, L2-cached)
        int e = i / 96;
        int o = i - e * 96;
        s_wt[i] = gpw[o * 96 + e];
    }
    for (int i = t; i < 384; i += TPB) {
        int s = i / 96;
        int e = i - s * 96;
        s_gamma[s * 97 + e] = ggamma[i];
        s_beta [s * 97 + e] = gbeta[i];
    }
    if (t < 96) s_pb[t] = gpb[t];
    __syncthreads();

    const int p_a = t >> 2, s_a = t & 3;          // staging assignment
    const int g_a = seq_of(p_a, s_a);
    const size_t rowoff = ((size_t)w * 256 + g_a) * 96;
    const float mu = s_mu[p_a];
    const float rs = s_rs[p_a];
    const int tq = t >> 4, tk = t & 15;           // 4x4 register-tile assignment
    const int mbase = (w % nwm) * 4096;

    for (int n = 0; n < 6; ++n) {
        // ---------------- phase A: stage qn / k / v head tiles ----------------
        {
            const float4* qp4 = (const float4*)(gq + rowoff + n * 16);
            const float4* kp4 = (const float4*)(gk + rowoff + n * 16);
            const float4* vp4 = (const float4*)(gv + rowoff + n * 16);
            float* dq = s_qh + p_a * 66 + s_a * 16;
            float* dk = s_kh + p_a * 66 + s_a * 16;
            float* dv = s_vh + p_a * 66 + s_a * 16;
            const float* ga = s_gamma + s_a * 97 + n * 16;
            const float* be = s_beta  + s_a * 97 + n * 16;
#pragma unroll
            for (int c4 = 0; c4 < 4; ++c4) {
                float4 qv = qp4[c4];
                float4 kv = kp4[c4];
                float4 vv = vp4[c4];
                float q0 = ((qv.x - mu) * rs * ga[4 * c4 + 0] + be[4 * c4 + 0]) * 0.125f;
                float q1 = ((qv.y - mu) * rs * ga[4 * c4 + 1] + be[4 * c4 + 1]) * 0.125f;
                float q2 = ((qv.z - mu) * rs * ga[4 * c4 + 2] + be[4 * c4 + 2]) * 0.125f;
                float q3 = ((qv.w - mu) * rs * ga[4 * c4 + 3] + be[4 * c4 + 3]) * 0.125f;
                ((float2*)(dq + 4 * c4))[0] = make_float2(q0, q1);
                ((float2*)(dq + 4 * c4))[1] = make_float2(q2, q3);
                ((float2*)(dk + 4 * c4))[0] = make_float2(kv.x, kv.y);
                ((float2*)(dk + 4 * c4))[1] = make_float2(kv.z, kv.w);
                ((float2*)(dv + 4 * c4))[0] = make_float2(vv.x, vv.y);
                ((float2*)(dv + 4 * c4))[1] = make_float2(vv.z, vv.w);
            }
        }
        __syncthreads();

        // ---------------- phase B: QK^T + bias + mask + softmax ----------------
        float acc[4][4];
#pragma unroll
        for (int i = 0; i < 4; ++i)
#pragma unroll
            for (int j = 0; j < 4; ++j) acc[i][j] = 0.f;
        {
            const float* qr = s_qh + tq * 66;
            const float* kr = s_kh + tk * 66;
#pragma unroll 8
            for (int c = 0; c < 64; c += 2) {
                float2 qv[4], kv[4];
#pragma unroll
                for (int i = 0; i < 4; ++i) qv[i] = *(const float2*)(qr + i * (16 * 66) + c);
#pragma unroll
                for (int j = 0; j < 4; ++j) kv[j] = *(const float2*)(kr + j * (16 * 66) + c);
#pragma unroll
                for (int i = 0; i < 4; ++i)
#pragma unroll
                    for (int j = 0; j < 4; ++j)
                        acc[i][j] = fmaf(qv[i].y, kv[j].y, fmaf(qv[i].x, kv[j].x, acc[i][j]));
            }
        }
#pragma unroll
        for (int i = 0; i < 4; ++i) {
            const int qp = tq + 16 * i;
            const int iq = qp >> 3, jq = qp & 7;
            float mx = -3.0e38f;
#pragma unroll
            for (int j = 0; j < 4; ++j) {
                const int kp = tk + 16 * j;
                const int ik = kp >> 3, jk = kp & 7;
                const int idx = (iq - ik + 7) * 15 + (jq - jk + 7);
                float a = acc[i][j] + gbt[idx * 6 + n] + gmask[mbase + qp * 64 + kp];
                acc[i][j] = a;
                mx = fmaxf(mx, a);
            }
            mx = fmaxf(mx, __shfl_xor(mx, 1));
            mx = fmaxf(mx, __shfl_xor(mx, 2));
            mx = fmaxf(mx, __shfl_xor(mx, 4));
            mx = fmaxf(mx, __shfl_xor(mx, 8));
            float sm = 0.f;
#pragma unroll
            for (int j = 0; j < 4; ++j) {
                float e = __expf(acc[i][j] - mx);
                acc[i][j] = e;
                sm += e;
            }
            sm += __shfl_xor(sm, 1);
            sm += __shfl_xor(sm, 2);
            sm += __shfl_xor(sm, 4);
            sm += __shfl_xor(sm, 8);
            const float inv = 1.0f / sm;
#pragma unroll
            for (int j = 0; j < 4; ++j) acc[i][j] *= inv;
        }
        __syncthreads();   // all reads of s_qh/s_kh done before overwriting s_qh
#pragma unroll
        for (int i = 0; i < 4; ++i)
#pragma unroll
            for (int j = 0; j < 4; ++j)
                s_qh[(tq + 16 * i) * 66 + tk + 16 * j] = acc[i][j];
        __syncthreads();

        // ---------------- phase C: PV -> bf16 out_pre ----------------
        float oacc[4][4];
#pragma unroll
        for (int i = 0; i < 4; ++i)
#pragma unroll
            for (int j = 0; j < 4; ++j) oacc[i][j] = 0.f;
        {
            const float* ar = s_qh + tq * 66;
#pragma unroll 4
            for (int kp = 0; kp < 64; kp += 2) {
                float2 av[4];
#pragma unroll
                for (int i = 0; i < 4; ++i) av[i] = *(const float2*)(ar + i * (16 * 66) + kp);
                float v0[4], v1[4];
#pragma unroll
                for (int j = 0; j < 4; ++j) {
                    v0[j] = s_vh[kp * 66 + tk + 16 * j];
                    v1[j] = s_vh[(kp + 1) * 66 + tk + 16 * j];
                }
#pragma unroll
                for (int i = 0; i < 4; ++i)
#pragma unroll
                    for (int j = 0; j < 4; ++j)
                        oacc[i][j] = fmaf(av[i].y, v1[j], fmaf(av[i].x, v0[j], oacc[i][j]));
            }
        }
        // value (i,j): token' = (tq+16i)*4 + j   (s = j), channel e = n*16 + tk (c = tk)
#pragma unroll
        for (int i = 0; i < 4; ++i)
#pragma unroll
            for (int j = 0; j < 4; ++j)
                s_pre[((tq + 16 * i) * 4 + j) * 98 + n * 16 + tk] = __float2bfloat16(oacc[i][j]);
        __syncthreads();
    }

    // ---------------- epilogue: projection + inverse grouping store ----------------
    {
        const int tr2 = t & 63, oc = t >> 6;   // rows {tr2+64i}, cols {oc*24 + j}
        float pacc[4][24];
#pragma unroll
        for (int i = 0; i < 4; ++i)
#pragma unroll
            for (int j = 0; j < 24; ++j) pacc[i][j] = 0.f;
#pragma unroll 2
        for (int e = 0; e < 96; ++e) {
            float pv_[4];
#pragma unroll
            for (int i = 0; i < 4; ++i)
                pv_[i] = __bfloat162float(s_pre[(tr2 + 64 * i) * 98 + e]);
            const float* wr = s_wt + e * 96 + oc * 24;
#pragma unroll
            for (int j4 = 0; j4 < 6; ++j4) {
                float4 ww = *(const float4*)(wr + 4 * j4);
#pragma unroll
                for (int i = 0; i < 4; ++i) {
                    pacc[i][j4 * 4 + 0] = fmaf(pv_[i], ww.x, pacc[i][j4 * 4 + 0]);
                    pacc[i][j4 * 4 + 1] = fmaf(pv_[i], ww.y, pacc[i][j4 * 4 + 1]);
                    pacc[i][j4 * 4 + 2] = fmaf(pv_[i], ww.z, pacc[i][j4 * 4 + 2]);
                    pacc[i][j4 * 4 + 3] = fmaf(pv_[i], ww.w, pacc[i][j4 * 4 + 3]);
                }
            }
        }
#pragma unroll
        for (int i = 0; i < 4; ++i) {
            const int tp = tr2 + 64 * i;
            const int p = tp >> 2, s = tp & 3;
            const int g = seq_of(p, s);
            float* orow = gout + ((size_t)w * 256 + g) * 96 + oc * 24;
#pragma unroll
            for (int j4 = 0; j4 < 6; ++j4) {
                float4 val;
                val.x = pacc[i][j4 * 4 + 0] + s_pb[oc * 24 + j4 * 4 + 0];
                val.y = pacc[i][j4 * 4 + 1] + s_pb[oc * 24 + j4 * 4 + 1];
                val.z = pacc[i][j4 * 4 + 2] + s_pb[oc * 24 + j4 * 4 + 2];
                val.w = pacc[i][j4 * 4 + 3] + s_pb[oc * 24 + j4 * 4 + 3];
                *(float4*)(orow + 4 * j4) = val;
            }
        }
    }
}

extern "C" void kernel_launch(void* const* d_in, const int* in_sizes, int n_in,
                              void* d_out, int out_size, void* d_ws, size_t ws_size,
                              hipStream_t stream) {
    const float* gq     = (const float*)d_in[0];
    const float* gk     = (const float*)d_in[1];
    const float* gv     = (const float*)d_in[2];
    const float* gmask  = (const float*)d_in[3];
    const float* gbt    = (const float*)d_in[4];
    const float* ggamma = (const float*)d_in[5];
    const float* gbeta  = (const float*)d_in[6];
    const float* gpw    = (const float*)d_in[7];
    const float* gpb    = (const float*)d_in[8];
    float* gout = (float*)d_out;

    const int nw  = in_sizes[0] / (256 * 96);
    const int nwm = in_sizes[3] / (64 * 64);

    dwa_fused<<<nw, TPB, 0, stream>>>(gq, gk, gv, gmask, gbt, ggamma, gbeta,
                                      gpw, gpb, gout, nwm);
}

// Round 4
// 599.167 us; speedup vs baseline: 1.3679x; 1.3679x over previous
//
#include <hip/hip_runtime.h>
#include <hip/hip_bf16.h>

// DiagonalWindowAttention fused MFMA kernel (v2: no tr_read; V staged transposed).
// One block per window (nw=2048), 256 threads = 4 waves.
//   phase 0 : LN stats per patch; stage gamma/beta to LDS
//   head n  : stage qn/k (swizzled bf16 [64][64]) + VT (V transposed, [n'][kp],
//             same swizzle) -> QK^T via mfma_16x16x32_bf16 -> bias+mask+softmax
//             (shfl) -> P bf16 to LDS -> PV via MFMA (B-frags = VT rows, same
//             read pattern as K) -> pre[256][32] per head-pair
//   pair m  : proj partial C += pre_pair . W[:, 32m:32m+32]^T via MFMA
//   epilogue: +bias, inverse group permutation, stores
//
// token grouping: p = wh*8+ww, s = sh*2+sw, seq g = wh*32+sh*16+ww*2+sw

#define TPB 256

// LDS byte offsets
#define Q0   0        // [64][64] bf16 swizzled (8 KB)
#define K0   8192
#define P0   16384
#define VT0  24576    // V^T per head: [n'=s*16+c][kp] bf16 swizzled (8 KB)
#define PR0  32768    // pre[256][32] bf16 (16 KB)
#define MU0  49152
#define RS0  49408
#define GA0  49664    // gamma fp32 [4][96]
#define BE0  51200    // beta  fp32 [4][96]
#define LDS_TOTAL 52736

typedef __attribute__((ext_vector_type(8))) short short8;
typedef __attribute__((ext_vector_type(4))) float f32x4;

union FRAG { uint4 u4; short8 s8; };

__device__ __forceinline__ int seq_of(int p, int s) {
    return ((p >> 3) << 5) | ((s >> 1) << 4) | ((p & 7) << 1) | (s & 1);
}

// swizzled byte address of 16B slot in a [64][64] bf16 tile (128B rows)
#define SWZ(row, slot) (((row) << 7) + ((((slot) ^ ((row) & 7))) << 4))

__device__ __forceinline__ unsigned short f2b(float x) {
    union { __hip_bfloat16 h; unsigned short u; } z;
    z.h = __float2bfloat16(x);
    return z.u;
}

__device__ __forceinline__ uint4 pack8(const float* v) {
    union { uint4 u4; unsigned short us[8]; } z;
#pragma unroll
    for (int i = 0; i < 8; ++i) z.us[i] = f2b(v[i]);
    return z.u4;
}

__global__ __launch_bounds__(TPB, 3)
void dwa_mfma(const float* __restrict__ gq,
              const float* __restrict__ gk,
              const float* __restrict__ gv,
              const float* __restrict__ gmask,
              const float* __restrict__ gbt,
              const float* __restrict__ ggamma,
              const float* __restrict__ gbeta,
              const float* __restrict__ gpw,
              const float* __restrict__ gpb,
              float* __restrict__ gout,
              int nwm)
{
    __shared__ __align__(16) unsigned char Lraw[LDS_TOTAL];
    char* L = (char*)Lraw;

    const int w = blockIdx.x;
    const int t = threadIdx.x;
    const int lane = t & 63, wv = t >> 6;
    const int r15 = lane & 15, gsl = lane >> 4;

    const int p_a = t >> 2, s_a = t & 3;
    const int g_a = seq_of(p_a, s_a);
    const size_t rowbase = ((size_t)w * 256 + g_a) * 96;
    const int mbase = (w % nwm) * 4096;

    float* s_mu = (float*)(L + MU0);
    float* s_rs = (float*)(L + RS0);
    float* s_ga = (float*)(L + GA0);
    float* s_be = (float*)(L + BE0);

    // ---------------- phase 0: LN stats + gamma/beta ----------------
    {
        const float4* qr = (const float4*)(gq + rowbase);
        float sum = 0.f, ssq = 0.f;
#pragma unroll
        for (int i = 0; i < 24; ++i) {
            float4 x = qr[i];
            sum += (x.x + x.y) + (x.z + x.w);
            ssq += (x.x * x.x + x.y * x.y) + (x.z * x.z + x.w * x.w);
        }
        sum += __shfl_xor(sum, 1); ssq += __shfl_xor(ssq, 1);
        sum += __shfl_xor(sum, 2); ssq += __shfl_xor(ssq, 2);
        if (s_a == 0) {
            float m_ = sum * (1.f / 384.f);
            s_mu[p_a] = m_;
            s_rs[p_a] = rsqrtf(ssq * (1.f / 384.f) - m_ * m_ + 1e-5f);
        }
    }
    for (int i = t; i < 384; i += TPB) {
        s_ga[i] = ggamma[i];
        s_be[i] = gbeta[i];
    }
    __syncthreads();
    const float mu = s_mu[p_a];
    const float rs = s_rs[p_a];

    const f32x4 zf = {0.f, 0.f, 0.f, 0.f};
    f32x4 pacc[4][6];
#pragma unroll
    for (int a = 0; a < 4; ++a)
#pragma unroll
        for (int b = 0; b < 6; ++b) pacc[a][b] = zf;

    const int qr0 = (wv << 4) + (gsl << 2);   // C-layout q-row base (+reg)

    for (int n = 0; n < 6; ++n) {
        // ------- stage q (LN'd) / k (row-major swz) and V transposed -------
        {
            const float* ga = s_ga + s_a * 96 + n * 16;
            const float* be = s_be + s_a * 96 + n * 16;
#pragma unroll
            for (int h = 0; h < 2; ++h) {     // 8 channels per pass
                const float* qs = gq + rowbase + n * 16 + h * 8;
                const float* ks = gk + rowbase + n * 16 + h * 8;
                const float* vs = gv + rowbase + n * 16 + h * 8;
                float4 q0 = ((const float4*)qs)[0], q1 = ((const float4*)qs)[1];
                float4 k0 = ((const float4*)ks)[0], k1 = ((const float4*)ks)[1];
                float4 v0 = ((const float4*)vs)[0], v1 = ((const float4*)vs)[1];
                float qv[8] = {q0.x, q0.y, q0.z, q0.w, q1.x, q1.y, q1.z, q1.w};
                float kv[8] = {k0.x, k0.y, k0.z, k0.w, k1.x, k1.y, k1.z, k1.w};
                float vv[8] = {v0.x, v0.y, v0.z, v0.w, v1.x, v1.y, v1.z, v1.w};
#pragma unroll
                for (int i = 0; i < 8; ++i)
                    qv[i] = ((qv[i] - mu) * rs * ga[h * 8 + i] + be[h * 8 + i]) * 0.125f;
                *(uint4*)(L + Q0 + SWZ(p_a, s_a * 2 + h)) = pack8(qv);
                *(uint4*)(L + K0 + SWZ(p_a, s_a * 2 + h)) = pack8(kv);
#pragma unroll
                for (int c = 0; c < 8; ++c) {
                    const int np_ = s_a * 16 + h * 8 + c;   // n' row of VT
                    *(unsigned short*)(L + VT0 + (np_ << 7) +
                        ((((p_a >> 3) ^ (np_ & 7))) << 4) + ((p_a & 7) << 1))
                        = f2b(vv[c]);
                }
            }
        }
        __syncthreads();

        // ---------------- QK^T ----------------
        FRAG a0, a1;
        a0.u4 = *(const uint4*)(L + Q0 + SWZ(wv * 16 + r15, gsl));
        a1.u4 = *(const uint4*)(L + Q0 + SWZ(wv * 16 + r15, 4 + gsl));
        f32x4 sacc[4];
#pragma unroll
        for (int tile = 0; tile < 4; ++tile) {
            FRAG b0, b1;
            b0.u4 = *(const uint4*)(L + K0 + SWZ(tile * 16 + r15, gsl));
            b1.u4 = *(const uint4*)(L + K0 + SWZ(tile * 16 + r15, 4 + gsl));
            sacc[tile] = __builtin_amdgcn_mfma_f32_16x16x32_bf16(a0.s8, b0.s8, zf, 0, 0, 0);
            sacc[tile] = __builtin_amdgcn_mfma_f32_16x16x32_bf16(a1.s8, b1.s8, sacc[tile], 0, 0, 0);
        }

        // ---------------- bias + mask + softmax + P store ----------------
#pragma unroll
        for (int r = 0; r < 4; ++r) {
            const int q = qr0 + r;
            const int iq = q >> 3, jq = q & 7;
            float vals[4];
            float mx = -3.0e38f;
#pragma unroll
            for (int tile = 0; tile < 4; ++tile) {
                const int kp = (tile << 4) + r15;
                const int ik = kp >> 3, jk = kp & 7;
                const float bv = gbt[((iq - ik + 7) * 15 + (jq - jk + 7)) * 6 + n];
                const float mv = gmask[mbase + (q << 6) + kp];
                float a = sacc[tile][r] + bv + mv;
                vals[tile] = a;
                mx = fmaxf(mx, a);
            }
            mx = fmaxf(mx, __shfl_xor(mx, 1));
            mx = fmaxf(mx, __shfl_xor(mx, 2));
            mx = fmaxf(mx, __shfl_xor(mx, 4));
            mx = fmaxf(mx, __shfl_xor(mx, 8));
            float sm = 0.f;
#pragma unroll
            for (int tile = 0; tile < 4; ++tile) {
                vals[tile] = __expf(vals[tile] - mx);
                sm += vals[tile];
            }
            sm += __shfl_xor(sm, 1);
            sm += __shfl_xor(sm, 2);
            sm += __shfl_xor(sm, 4);
            sm += __shfl_xor(sm, 8);
            const float inv = 1.0f / sm;
#pragma unroll
            for (int tile = 0; tile < 4; ++tile) {
                const int col = (tile << 4) + r15;
                *(unsigned short*)(L + P0 + (q << 7) +
                                   (((col >> 3) ^ (q & 7)) << 4) + ((col & 7) << 1))
                    = f2b(vals[tile] * inv);
            }
        }
        __syncthreads();

        // ---------------- PV: B-frags from VT (same pattern as K) ----------------
        FRAG pa0, pa1;
        pa0.u4 = *(const uint4*)(L + P0 + SWZ(wv * 16 + r15, gsl));
        pa1.u4 = *(const uint4*)(L + P0 + SWZ(wv * 16 + r15, 4 + gsl));
        f32x4 oacc[4];
#pragma unroll
        for (int ct = 0; ct < 4; ++ct) {
            FRAG b0, b1;
            b0.u4 = *(const uint4*)(L + VT0 + SWZ(ct * 16 + r15, gsl));
            b1.u4 = *(const uint4*)(L + VT0 + SWZ(ct * 16 + r15, 4 + gsl));
            oacc[ct] = __builtin_amdgcn_mfma_f32_16x16x32_bf16(pa0.s8, b0.s8, zf, 0, 0, 0);
            oacc[ct] = __builtin_amdgcn_mfma_f32_16x16x32_bf16(pa1.s8, b1.s8, oacc[ct], 0, 0, 0);
        }

        // pre[token = q*4 + s][ (n&1)*16 + hd ]
#pragma unroll
        for (int ct = 0; ct < 4; ++ct)
#pragma unroll
            for (int r = 0; r < 4; ++r) {
                const int token = ((qr0 + r) << 2) + ct;
                *(unsigned short*)(L + PR0 + token * 64 + (((n & 1) << 4) + r15) * 2)
                    = f2b(oacc[ct][r]);
            }
        __syncthreads();

        // ---------------- partial projection per head-pair ----------------
        if (n & 1) {
            const int m = n >> 1;
            FRAG pa[4];
#pragma unroll
            for (int rt = 0; rt < 4; ++rt) {
                const int row = (wv << 6) + (rt << 4) + r15;
                pa[rt].u4 = *(const uint4*)(L + PR0 + row * 64 + (gsl << 4));
            }
#pragma unroll
            for (int ct = 0; ct < 6; ++ct) {
                const int o = (ct << 4) + r15;
                const float4* wp = (const float4*)(gpw + o * 96 + (m << 5) + (gsl << 3));
                float4 w0 = wp[0], w1 = wp[1];
                float w8[8] = {w0.x, w0.y, w0.z, w0.w, w1.x, w1.y, w1.z, w1.w};
                FRAG bw;
                bw.u4 = pack8(w8);
#pragma unroll
                for (int rt = 0; rt < 4; ++rt)
                    pacc[rt][ct] = __builtin_amdgcn_mfma_f32_16x16x32_bf16(
                        pa[rt].s8, bw.s8, pacc[rt][ct], 0, 0, 0);
            }
        }
    }

    // ---------------- epilogue: +bias, inverse grouping, store ----------------
#pragma unroll
    for (int ct = 0; ct < 6; ++ct) {
        const int o = (ct << 4) + r15;
        const float pbv = gpb[o];
#pragma unroll
        for (int rt = 0; rt < 4; ++rt) {
#pragma unroll
            for (int r = 0; r < 4; ++r) {
                const int token = (wv << 6) + (rt << 4) + (gsl << 2) + r;
                const int p = token >> 2, s = token & 3;
                const int gsq = seq_of(p, s);
                gout[((size_t)w * 256 + gsq) * 96 + o] = pacc[rt][ct][r] + pbv;
            }
        }
    }
}

extern "C" void kernel_launch(void* const* d_in, const int* in_sizes, int n_in,
                              void* d_out, int out_size, void* d_ws, size_t ws_size,
                              hipStream_t stream) {
    const float* gq     = (const float*)d_in[0];
    const float* gk     = (const float*)d_in[1];
    const float* gv     = (const float*)d_in[2];
    const float* gmask  = (const float*)d_in[3];
    const float* gbt    = (const float*)d_in[4];
    const float* ggamma = (const float*)d_in[5];
    const float* gbeta  = (const float*)d_in[6];
    const float* gpw    = (const float*)d_in[7];
    const float* gpb    = (const float*)d_in[8];
    float* gout = (float*)d_out;

    const int nw  = in_sizes[0] / (256 * 96);
    const int nwm = in_sizes[3] / (64 * 64);

    dwa_mfma<<<nw, TPB, 0, stream>>>(gq, gk, gv, gmask, gbt, ggamma, gbeta,
                                     gpw, gpb, gout, nwm);
}